// Round 1
// baseline (1087.974 us; speedup 1.0000x reference)
//
#include <hip/hip_runtime.h>

// TransformerBlock on MI355X (gfx950). B=2 T=2048 D_MODEL=2048 H=16 HD=128 D_FF=5504.
// Round 6: flash_attn rework —
//   * grid (32,32): one q-tile per block (qt = 31-bx, heavy blocks first) -> 1024 blocks
//   * LDS 40KB (Ks 16K + Vt 16K + Ps 8K), XOR-swizzle byte^=((row&7)<<4) instead of padding
//     -> 4 blocks/CU (was grid-limited to 2) and ~conflict-free b128 reads
//   * K tile staged via global_load_lds with PRE-SWIZZLED global source (linear LDS dest),
//     removing the K global->VGPR->LDS round trip.

using bf16 = __bf16;
typedef __bf16 bf16x2 __attribute__((ext_vector_type(2)));
typedef __bf16 bf16x8 __attribute__((ext_vector_type(8)));
typedef float f32x4 __attribute__((ext_vector_type(4)));

#define MFMA_BF16(a, b, c) __builtin_amdgcn_mfma_f32_16x16x32_bf16((a), (b), (c), 0, 0, 0)

__device__ __forceinline__ void gld_lds16(const void* g, void* l) {
  // async global->LDS; LDS dst = wave-uniform base + lane*16 (HW rule).
  __builtin_amdgcn_global_load_lds((const __attribute__((address_space(1))) void*)g,
                                   (__attribute__((address_space(3))) void*)l,
                                   16, 0, 0);
}

// ---------------------------------------------------------------------------
// Detect input dtype (fp32 vs bf16) from x's first 64 words. flag=1 -> bf16.
// ---------------------------------------------------------------------------
__global__ void detect_dtype(const unsigned int* __restrict__ X, int* __restrict__ flag) {
  const int tid = threadIdx.x;  // 64 threads = 1 wave
  const unsigned int w = X[tid];
  const unsigned int e_lo = (w >> 7) & 0xFF;
  const unsigned int e_hi = (w >> 23) & 0xFF;
  const bool sane = (e_lo >= 97u && e_lo <= 157u) && (e_hi >= 97u && e_hi <= 157u);
  const unsigned long long m = __ballot(sane);
  if (tid == 0) *flag = (__popcll(m) > 48) ? 1 : 0;
}

__global__ __launch_bounds__(256) void convert_in(const void* __restrict__ src,
                                                  bf16* __restrict__ dst,
                                                  const int* __restrict__ flag) {
  const size_t i = ((size_t)blockIdx.x * 256 + threadIdx.x) * 8;
  if (*flag) {
    *(bf16x8*)(dst + i) = *(const bf16x8*)((const bf16*)src + i);
  } else {
    const float* s = (const float*)src;
    float4 a = *(const float4*)(s + i);
    float4 b = *(const float4*)(s + i + 4);
    bf16x8 o;
    o[0] = (bf16)a.x; o[1] = (bf16)a.y; o[2] = (bf16)a.z; o[3] = (bf16)a.w;
    o[4] = (bf16)b.x; o[5] = (bf16)b.y; o[6] = (bf16)b.z; o[7] = (bf16)b.w;
    *(bf16x8*)(dst + i) = o;
  }
}

// ---------------------------------------------------------------------------
// RMSNorm kernels (fp32 math).
// ---------------------------------------------------------------------------
__global__ __launch_bounds__(256) void rmsnorm_bf16(const bf16* __restrict__ X,
                                                    const bf16* __restrict__ g,
                                                    bf16* __restrict__ Hout) {
  const int row = blockIdx.x, tid = threadIdx.x;
  const size_t off = (size_t)row * 2048 + tid * 8;
  bf16x8 x8 = *(const bf16x8*)(X + off);
  float v[8];
  float s = 0.f;
#pragma unroll
  for (int j = 0; j < 8; ++j) { v[j] = (float)x8[j]; s += v[j] * v[j]; }
#pragma unroll
  for (int o = 32; o; o >>= 1) s += __shfl_xor(s, o);
  __shared__ float red[4];
  if ((tid & 63) == 0) red[tid >> 6] = s;
  __syncthreads();
  const float tot = red[0] + red[1] + red[2] + red[3];
  const float inv = 1.f / (sqrtf(tot * (1.f / 2048.f)) + 1e-8f);
  bf16x8 g8 = *(const bf16x8*)(g + tid * 8);
  bf16x8 o8;
#pragma unroll
  for (int j = 0; j < 8; ++j) o8[j] = (bf16)((float)g8[j] * v[j] * inv);
  *(bf16x8*)(Hout + off) = o8;
}

__global__ __launch_bounds__(256) void rmsnorm_f32(const float* __restrict__ X,
                                                   const bf16* __restrict__ g,
                                                   bf16* __restrict__ Hout) {
  const int row = blockIdx.x, tid = threadIdx.x;
  const size_t off = (size_t)row * 2048 + tid * 8;
  float4 a0 = *(const float4*)(X + off);
  float4 a1 = *(const float4*)(X + off + 4);
  float v[8] = {a0.x, a0.y, a0.z, a0.w, a1.x, a1.y, a1.z, a1.w};
  float s = 0.f;
#pragma unroll
  for (int j = 0; j < 8; ++j) s += v[j] * v[j];
#pragma unroll
  for (int o = 32; o; o >>= 1) s += __shfl_xor(s, o);
  __shared__ float red[4];
  if ((tid & 63) == 0) red[tid >> 6] = s;
  __syncthreads();
  const float tot = red[0] + red[1] + red[2] + red[3];
  const float inv = 1.f / (sqrtf(tot * (1.f / 2048.f)) + 1e-8f);
  bf16x8 g8 = *(const bf16x8*)(g + tid * 8);
  bf16x8 o8;
#pragma unroll
  for (int j = 0; j < 8; ++j) o8[j] = (bf16)((float)g8[j] * v[j] * inv);
  *(bf16x8*)(Hout + off) = o8;
}

// ---------------------------------------------------------------------------
// RoPE in-place on Q and K.
// ---------------------------------------------------------------------------
__global__ __launch_bounds__(256) void rope_k(bf16* __restrict__ Q, bf16* __restrict__ Kg,
                                              const bf16* __restrict__ cosb,
                                              const bf16* __restrict__ sinb) {
  const int tid = threadIdx.x;
  const int rr = tid >> 7;
  const int c = tid & 127;
  const int bt = blockIdx.x * 2 + rr;
  const int t = bt & 2047;
  const int h = c >> 3;
  const int d0 = (c & 7) * 8;
  const size_t row = (size_t)bt * 2048;
  const int i0 = h * 128 + d0;
  bf16x8 c0 = *(const bf16x8*)(cosb + t * 128 + d0);
  bf16x8 c1 = *(const bf16x8*)(cosb + t * 128 + d0 + 64);
  bf16x8 s0 = *(const bf16x8*)(sinb + t * 128 + d0);
  bf16x8 s1 = *(const bf16x8*)(sinb + t * 128 + d0 + 64);
  bf16x8 qa = *(const bf16x8*)(Q + row + i0);
  bf16x8 qb = *(const bf16x8*)(Q + row + i0 + 64);
  bf16x8 ka = *(const bf16x8*)(Kg + row + i0);
  bf16x8 kb = *(const bf16x8*)(Kg + row + i0 + 64);
  bf16x8 qo0, qo1, ko0, ko1;
#pragma unroll
  for (int j = 0; j < 8; ++j) {
    float cj0 = (float)c0[j], cj1 = (float)c1[j];
    float sj0 = (float)s0[j], sj1 = (float)s1[j];
    float qaj = (float)qa[j], qbj = (float)qb[j];
    float kaj = (float)ka[j], kbj = (float)kb[j];
    qo0[j] = (bf16)(qaj * cj0 - qbj * sj0);
    qo1[j] = (bf16)(qbj * cj1 + qaj * sj1);
    ko0[j] = (bf16)(kaj * cj0 - kbj * sj0);
    ko1[j] = (bf16)(kbj * cj1 + kaj * sj1);
  }
  *(bf16x8*)(Q + row + i0) = qo0;
  *(bf16x8*)(Q + row + i0 + 64) = qo1;
  *(bf16x8*)(Kg + row + i0) = ko0;
  *(bf16x8*)(Kg + row + i0 + 64) = ko1;
}

// ---------------------------------------------------------------------------
// GEMM C = A(MxK) * W(NxK)^T, bf16 MFMA 16x16x32, 128x128 tile, 4 waves 2x2.
// Double-buffered LDS: stage(k+1) issued after the barrier, overlapping MFMA(k).
// EPI: 0 bf16; 1 fp32 = v + bf16 res; 2 silu->bf16; 3 v*mulb->bf16;
//      4 fp32 res + v -> d_out (dtype per oflag).
// ---------------------------------------------------------------------------
template <int EPI>
__global__ __launch_bounds__(256) void gemm_bt(const bf16* __restrict__ A,
                                               const bf16* __restrict__ W,
                                               bf16* __restrict__ Cb, float* __restrict__ Cf,
                                               const bf16* __restrict__ resb,
                                               const float* __restrict__ resf,
                                               const bf16* __restrict__ mulb,
                                               const int* __restrict__ oflag,
                                               int M, int N, int K) {
  __shared__ bf16 As[2][128 * 32];
  __shared__ bf16 Ws[2][128 * 32];
  const int tid = threadIdx.x;
  const int wave = tid >> 6, lane = tid & 63;
  const int quad = lane >> 4, l15 = lane & 15;
  const int wm = wave >> 1, wn = wave & 1;
  const int m0 = blockIdx.y * 128, n0 = blockIdx.x * 128;

  f32x4 acc[4][4];
#pragma unroll
  for (int i = 0; i < 4; ++i)
#pragma unroll
    for (int j = 0; j < 4; ++j) acc[i][j] = {0.f, 0.f, 0.f, 0.f};

  const int srow = lane >> 2;       // 0..15
  const int skk = (lane & 3) * 8;   // 0,8,16,24
  const bf16* Ab = A + (size_t)m0 * K;
  const bf16* Wb = W + (size_t)n0 * K;

  // stage one 128x32 K-slice of A and W into buffer `buf` (async, 16B/lane)
  auto stage = [&](int buf, int kb) {
    const int k0 = kb << 5;
#pragma unroll
    for (int c = 0; c < 2; ++c) {
      const int r = (wave * 2 + c) * 16 + srow;
      gld_lds16(Ab + (size_t)r * K + k0 + skk, (char*)As[buf] + (wave * 2 + c) * 1024);
      gld_lds16(Wb + (size_t)r * K + k0 + skk, (char*)Ws[buf] + (wave * 2 + c) * 1024);
    }
  };
  // ds_read frags from buffer `buf` and run 16 MFMAs
  auto compute = [&](int buf) {
    bf16x8 af[4], wf[4];
#pragma unroll
    for (int mt = 0; mt < 4; ++mt)
      af[mt] = *(const bf16x8*)&As[buf][(wm * 64 + mt * 16 + l15) * 32 + quad * 8];
#pragma unroll
    for (int nt = 0; nt < 4; ++nt)
      wf[nt] = *(const bf16x8*)&Ws[buf][(wn * 64 + nt * 16 + l15) * 32 + quad * 8];
#pragma unroll
    for (int mt = 0; mt < 4; ++mt)
#pragma unroll
      for (int nt = 0; nt < 4; ++nt)
        acc[mt][nt] = MFMA_BF16(af[mt], wf[nt], acc[mt][nt]);
  };

  const int nk = K >> 5;  // always even here (64 or 172)
  stage(0, 0);
  for (int kb = 0; kb < nk; kb += 2) {
    __syncthreads();                     // buf0 loads drained (vmcnt0) + reads of buf0 done
    if (kb + 1 < nk) stage(1, kb + 1);   // overlaps compute(buf0)
    compute(0);
    __syncthreads();                     // buf1 loads drained + reads of buf1 done
    if (kb + 2 < nk) stage(0, kb + 2);   // overlaps compute(buf1)
    compute(1);
  }

  const int obf = (EPI == 4 && oflag) ? *oflag : 0;
#pragma unroll
  for (int mt = 0; mt < 4; ++mt) {
#pragma unroll
    for (int nt = 0; nt < 4; ++nt) {
#pragma unroll
      for (int r = 0; r < 4; ++r) {
        const int row = m0 + wm * 64 + mt * 16 + quad * 4 + r;
        const int col = n0 + wn * 64 + nt * 16 + l15;
        const size_t idx = (size_t)row * N + col;
        const float v = acc[mt][nt][r];
        if constexpr (EPI == 0) {
          Cb[idx] = (bf16)v;
        } else if constexpr (EPI == 1) {
          Cf[idx] = v + (float)resb[idx];
        } else if constexpr (EPI == 2) {
          Cb[idx] = (bf16)(v / (1.f + __expf(-v)));   // silu
        } else if constexpr (EPI == 3) {
          Cb[idx] = (bf16)((float)mulb[idx] * v);
        } else {  // EPI == 4: final output, dtype per flag
          const float rres = resf[idx] + v;
          if (obf) Cb[idx] = (bf16)rres;
          else     Cf[idx] = rres;
        }
      }
    }
  }
}

// ---------------------------------------------------------------------------
// Flash attention (causal). Grid (32, B*H); block x handles q-tile 31-x
// (heaviest first). LDS 40KB -> 4 blocks/CU. All tiles XOR-swizzled
// (byte ^= ((row&7)<<4)) instead of padded: conflict-free b128 reads.
// K staged by global_load_lds with pre-swizzled SOURCE (linear LDS dest).
// ---------------------------------------------------------------------------
__global__ __launch_bounds__(256) void flash_attn(const bf16* __restrict__ Q,
                                                  const bf16* __restrict__ Kg,
                                                  const bf16* __restrict__ Vg,
                                                  bf16* __restrict__ O) {
  __shared__ bf16 Ks[64 * 128];    // K rows, 256B/row, chunk-swizzled
  __shared__ bf16 Vt[128 * 64];    // V^T rows (d-major), 128B/row, swizzled
  __shared__ bf16 Ps[4 * 16 * 64]; // per-wave P tile, 128B/row, swizzled
  const int tid = threadIdx.x;
  const int wave = tid >> 6, lane = tid & 63;
  const int quad = lane >> 4, l15 = lane & 15;
  const int bh = blockIdx.y;
  const int b = bh >> 4, h = bh & 15;
  const size_t base = (size_t)b * 2048 * 2048 + h * 128;
  const float scale = 0.08838834764831845f;  // 1/sqrt(128)

  const int qt = 31 - (int)blockIdx.x;   // heavy tiles launch first
  const int q0 = qt * 64;

  bf16x8 qf[4];
  {
    const bf16* qrow = Q + base + (size_t)(q0 + wave * 16 + l15) * 2048;
#pragma unroll
    for (int ks = 0; ks < 4; ++ks) qf[ks] = *(const bf16x8*)(qrow + ks * 32 + quad * 8);
  }

  f32x4 o[8];
#pragma unroll
  for (int i = 0; i < 8; ++i) o[i] = {0.f, 0.f, 0.f, 0.f};
  float m_r[4] = {-1e30f, -1e30f, -1e30f, -1e30f};
  float l_r[4] = {0.f, 0.f, 0.f, 0.f};

  for (int kb = 0; kb <= qt; ++kb) {
    const int k0 = kb * 64;
    __syncthreads();  // prev iter's LDS reads done before restaging

    // ---- K tile: async DMA, source pre-swizzled so swizzled reads see K[row][col]
#pragma unroll
    for (int c = 0; c < 4; ++c) {
      const int ch = tid + 256 * c;
      const int row = ch >> 4;
      const int scb = ((ch & 15) * 16) ^ ((row & 7) << 4);  // swizzled src byte col
      gld_lds16((const char*)(Kg + base + (size_t)(k0 + row) * 2048) + scb,
                (char*)Ks + wave * 1024 + c * 4096);        // wave-uniform + lane*16
    }
    // ---- V tile: reg transpose into swizzled Vt (V^T[d][k])
#pragma unroll
    for (int c = 0; c < 2; ++c) {
      const int tau = tid + 256 * c;
      const int kp = tau & 31;
      const int d0 = (tau >> 5) * 8;
      bf16x8 va = *(const bf16x8*)(Vg + base + (size_t)(k0 + 2 * kp) * 2048 + d0);
      bf16x8 vb = *(const bf16x8*)(Vg + base + (size_t)(k0 + 2 * kp + 1) * 2048 + d0);
#pragma unroll
      for (int j = 0; j < 8; ++j) {
        bf16x2 pr = {va[j], vb[j]};
        const int d = d0 + j;
        *(bf16x2*)((char*)Vt + d * 128 + ((4 * kp) ^ ((d & 7) << 4))) = pr;
      }
    }
    __syncthreads();  // drains vmcnt (K DMA done) + Vt visible

    f32x4 s[4];
#pragma unroll
    for (int nt = 0; nt < 4; ++nt) {
      s[nt] = {0.f, 0.f, 0.f, 0.f};
      const int krow = nt * 16 + l15;
#pragma unroll
      for (int ks = 0; ks < 4; ++ks) {
        bf16x8 kf = *(const bf16x8*)((char*)Ks + krow * 256 +
                                     ((ks * 64 + quad * 16) ^ ((krow & 7) << 4)));
        s[nt] = MFMA_BF16(qf[ks], kf, s[nt]);
      }
    }

    float sv[4][4];
#pragma unroll
    for (int nt = 0; nt < 4; ++nt) {
#pragma unroll
      for (int r = 0; r < 4; ++r) {
        float v = s[nt][r] * scale;
        const int key = k0 + nt * 16 + l15;
        const int qq = q0 + wave * 16 + quad * 4 + r;
        if (key > qq) v = -1e9f;
        sv[nt][r] = v;
      }
    }

#pragma unroll
    for (int r = 0; r < 4; ++r) {
      float rmax = fmaxf(fmaxf(sv[0][r], sv[1][r]), fmaxf(sv[2][r], sv[3][r]));
#pragma unroll
      for (int off = 1; off < 16; off <<= 1) rmax = fmaxf(rmax, __shfl_xor(rmax, off));
      const float mnew = fmaxf(m_r[r], rmax);
      const float alpha = __expf(m_r[r] - mnew);
      float psum = 0.f;
      const int qrow = quad * 4 + r;
#pragma unroll
      for (int nt = 0; nt < 4; ++nt) {
        const float p = __expf(sv[nt][r] - mnew);
        psum += p;
        *(bf16*)((char*)Ps + wave * 2048 + qrow * 128 +
                 ((2 * (nt * 16 + l15)) ^ ((qrow & 7) << 4))) = (bf16)p;
      }
#pragma unroll
      for (int off = 1; off < 16; off <<= 1) psum += __shfl_xor(psum, off);
      l_r[r] = l_r[r] * alpha + psum;
      m_r[r] = mnew;
#pragma unroll
      for (int nt2 = 0; nt2 < 8; ++nt2) o[nt2][r] *= alpha;
    }

    asm volatile("s_waitcnt lgkmcnt(0)" ::: "memory");

#pragma unroll
    for (int ks2 = 0; ks2 < 2; ++ks2) {
      bf16x8 pf = *(const bf16x8*)((char*)Ps + wave * 2048 + l15 * 128 +
                                   ((ks2 * 64 + quad * 16) ^ ((l15 & 7) << 4)));
#pragma unroll
      for (int nt2 = 0; nt2 < 8; ++nt2) {
        const int drow = nt2 * 16 + l15;
        bf16x8 vf = *(const bf16x8*)((char*)Vt + drow * 128 +
                                     ((ks2 * 64 + quad * 16) ^ ((drow & 7) << 4)));
        o[nt2] = MFMA_BF16(pf, vf, o[nt2]);
      }
    }
  }

#pragma unroll
  for (int nt2 = 0; nt2 < 8; ++nt2) {
#pragma unroll
    for (int r = 0; r < 4; ++r) {
      const int qq = q0 + wave * 16 + quad * 4 + r;
      const int dd = nt2 * 16 + l15;
      O[base + (size_t)qq * 2048 + dd] = (bf16)(o[nt2][r] / l_r[r]);
    }
  }
}

// ---------------------------------------------------------------------------
extern "C" void kernel_launch(void* const* d_in, const int* in_sizes, int n_in,
                              void* d_out, int out_size, void* d_ws, size_t ws_size,
                              hipStream_t stream) {
  const void* x_raw = d_in[0];
  const void* cos_raw = d_in[1];
  const void* sin_raw = d_in[2];
  // d_in[3] = mask — causal, applied analytically in flash_attn
  const void* g1_raw = d_in[4];
  const void* g2_raw = d_in[5];
  const void* W_raw[7] = {d_in[6], d_in[7], d_in[8], d_in[9], d_in[10], d_in[11], d_in[12]};

  char* ws = (char*)d_ws;
  const size_t MB = 1048576ull;
  int* flag = (int*)ws;
  bf16* g1c = (bf16*)(ws + 4096);
  bf16* g2c = (bf16*)(ws + 12288);
  bf16* cosc = (bf16*)(ws + 65536);          // 512KB
  bf16* sinc = (bf16*)(ws + 655360);         // 512KB
  bf16* xc   = (bf16*)(ws + 2 * MB);         // 16MB  [2,18)
  bf16* wslot= (bf16*)(ws + 18 * MB);        // 23MB  [18,41)
  bf16* hbuf = (bf16*)(ws + 41 * MB);        // 16MB  [41,57)
  bf16* qbuf = (bf16*)(ws + 57 * MB);        // 16MB  [57,73)
  bf16* kbuf = (bf16*)(ws + 73 * MB);        // 16MB  [73,89)
  bf16* vbuf = (bf16*)(ws + 89 * MB);        // 16MB  [89,105)
  bf16* abuf = (bf16*)(ws + 105 * MB);       // 16MB  [105,121)
  float* x1  = (float*)(ws + 57 * MB);       // 32MB over q,k (dead after flash)
  bf16* h2   = (bf16*)(ws + 41 * MB);        // over h (dead after V gemm)
  bf16* ubuf = (bf16*)(ws + 89 * MB);        // 43MB over v,attn [89,132)

  const int M = 4096;  // B*T
  dim3 blk(256);

  detect_dtype<<<1, 64, 0, stream>>>((const unsigned int*)x_raw, flag);

  convert_in<<<4096, blk, 0, stream>>>(x_raw, xc, flag);
  convert_in<<<128, blk, 0, stream>>>(cos_raw, cosc, flag);
  convert_in<<<128, blk, 0, stream>>>(sin_raw, sinc, flag);
  convert_in<<<1, blk, 0, stream>>>(g1_raw, g1c, flag);
  convert_in<<<1, blk, 0, stream>>>(g2_raw, g2c, flag);

  rmsnorm_bf16<<<M, blk, 0, stream>>>(xc, g1c, hbuf);

  convert_in<<<2048, blk, 0, stream>>>(W_raw[0], wslot, flag);
  gemm_bt<0><<<dim3(16, 32), blk, 0, stream>>>(hbuf, wslot, qbuf, nullptr, nullptr, nullptr, nullptr, nullptr, M, 2048, 2048);
  convert_in<<<2048, blk, 0, stream>>>(W_raw[1], wslot, flag);
  gemm_bt<0><<<dim3(16, 32), blk, 0, stream>>>(hbuf, wslot, kbuf, nullptr, nullptr, nullptr, nullptr, nullptr, M, 2048, 2048);
  convert_in<<<2048, blk, 0, stream>>>(W_raw[2], wslot, flag);
  gemm_bt<0><<<dim3(16, 32), blk, 0, stream>>>(hbuf, wslot, vbuf, nullptr, nullptr, nullptr, nullptr, nullptr, M, 2048, 2048);

  rope_k<<<M / 2, blk, 0, stream>>>(qbuf, kbuf, cosc, sinc);
  flash_attn<<<dim3(32, 32), blk, 0, stream>>>(qbuf, kbuf, vbuf, abuf);

  convert_in<<<2048, blk, 0, stream>>>(W_raw[3], wslot, flag);
  gemm_bt<1><<<dim3(16, 32), blk, 0, stream>>>(abuf, wslot, nullptr, x1, xc, nullptr, nullptr, nullptr, M, 2048, 2048);

  rmsnorm_f32<<<M, blk, 0, stream>>>(x1, g2c, h2);

  convert_in<<<5504, blk, 0, stream>>>(W_raw[4], wslot, flag);
  gemm_bt<2><<<dim3(43, 32), blk, 0, stream>>>(h2, wslot, ubuf, nullptr, nullptr, nullptr, nullptr, nullptr, M, 5504, 2048);
  convert_in<<<5504, blk, 0, stream>>>(W_raw[5], wslot, flag);
  gemm_bt<3><<<dim3(43, 32), blk, 0, stream>>>(h2, wslot, ubuf, nullptr, nullptr, nullptr, ubuf, nullptr, M, 5504, 2048);
  convert_in<<<5504, blk, 0, stream>>>(W_raw[6], wslot, flag);
  gemm_bt<4><<<dim3(16, 32), blk, 0, stream>>>(ubuf, wslot, (bf16*)d_out, (float*)d_out, nullptr, x1, nullptr, flag, M, 2048, 5504);
}

// Round 2
// 1071.705 us; speedup vs baseline: 1.0152x; 1.0152x over previous
//
#include <hip/hip_runtime.h>

// TransformerBlock on MI355X (gfx950). B=2 T=2048 D_MODEL=2048 H=16 HD=128 D_FF=5504.
// Round 7: flash_attn — balanced paired grid (16,32) restored (qt = x and 31-x, 33 iters
// per block); K/V LDS double-buffered (72KB, 2 blocks/CU); ONE barrier per k-iteration;
// all global traffic (K via global_load_lds w/ pre-swizzled source, V via reg-stage)
// issued a full iteration ahead so load latency hides under QK+softmax+PV.
// XOR-swizzled LDS (byte ^= ((row&7)<<4)) throughout — conflict-free b128 reads.

using bf16 = __bf16;
typedef __bf16 bf16x2 __attribute__((ext_vector_type(2)));
typedef __bf16 bf16x8 __attribute__((ext_vector_type(8)));
typedef float f32x4 __attribute__((ext_vector_type(4)));

#define MFMA_BF16(a, b, c) __builtin_amdgcn_mfma_f32_16x16x32_bf16((a), (b), (c), 0, 0, 0)

__device__ __forceinline__ void gld_lds16(const void* g, void* l) {
  // async global->LDS; LDS dst = wave-uniform base + lane*16 (HW rule).
  __builtin_amdgcn_global_load_lds((const __attribute__((address_space(1))) void*)g,
                                   (__attribute__((address_space(3))) void*)l,
                                   16, 0, 0);
}

// ---------------------------------------------------------------------------
// Detect input dtype (fp32 vs bf16) from x's first 64 words. flag=1 -> bf16.
// ---------------------------------------------------------------------------
__global__ void detect_dtype(const unsigned int* __restrict__ X, int* __restrict__ flag) {
  const int tid = threadIdx.x;  // 64 threads = 1 wave
  const unsigned int w = X[tid];
  const unsigned int e_lo = (w >> 7) & 0xFF;
  const unsigned int e_hi = (w >> 23) & 0xFF;
  const bool sane = (e_lo >= 97u && e_lo <= 157u) && (e_hi >= 97u && e_hi <= 157u);
  const unsigned long long m = __ballot(sane);
  if (tid == 0) *flag = (__popcll(m) > 48) ? 1 : 0;
}

__global__ __launch_bounds__(256) void convert_in(const void* __restrict__ src,
                                                  bf16* __restrict__ dst,
                                                  const int* __restrict__ flag) {
  const size_t i = ((size_t)blockIdx.x * 256 + threadIdx.x) * 8;
  if (*flag) {
    *(bf16x8*)(dst + i) = *(const bf16x8*)((const bf16*)src + i);
  } else {
    const float* s = (const float*)src;
    float4 a = *(const float4*)(s + i);
    float4 b = *(const float4*)(s + i + 4);
    bf16x8 o;
    o[0] = (bf16)a.x; o[1] = (bf16)a.y; o[2] = (bf16)a.z; o[3] = (bf16)a.w;
    o[4] = (bf16)b.x; o[5] = (bf16)b.y; o[6] = (bf16)b.z; o[7] = (bf16)b.w;
    *(bf16x8*)(dst + i) = o;
  }
}

// ---------------------------------------------------------------------------
// RMSNorm kernels (fp32 math).
// ---------------------------------------------------------------------------
__global__ __launch_bounds__(256) void rmsnorm_bf16(const bf16* __restrict__ X,
                                                    const bf16* __restrict__ g,
                                                    bf16* __restrict__ Hout) {
  const int row = blockIdx.x, tid = threadIdx.x;
  const size_t off = (size_t)row * 2048 + tid * 8;
  bf16x8 x8 = *(const bf16x8*)(X + off);
  float v[8];
  float s = 0.f;
#pragma unroll
  for (int j = 0; j < 8; ++j) { v[j] = (float)x8[j]; s += v[j] * v[j]; }
#pragma unroll
  for (int o = 32; o; o >>= 1) s += __shfl_xor(s, o);
  __shared__ float red[4];
  if ((tid & 63) == 0) red[tid >> 6] = s;
  __syncthreads();
  const float tot = red[0] + red[1] + red[2] + red[3];
  const float inv = 1.f / (sqrtf(tot * (1.f / 2048.f)) + 1e-8f);
  bf16x8 g8 = *(const bf16x8*)(g + tid * 8);
  bf16x8 o8;
#pragma unroll
  for (int j = 0; j < 8; ++j) o8[j] = (bf16)((float)g8[j] * v[j] * inv);
  *(bf16x8*)(Hout + off) = o8;
}

__global__ __launch_bounds__(256) void rmsnorm_f32(const float* __restrict__ X,
                                                   const bf16* __restrict__ g,
                                                   bf16* __restrict__ Hout) {
  const int row = blockIdx.x, tid = threadIdx.x;
  const size_t off = (size_t)row * 2048 + tid * 8;
  float4 a0 = *(const float4*)(X + off);
  float4 a1 = *(const float4*)(X + off + 4);
  float v[8] = {a0.x, a0.y, a0.z, a0.w, a1.x, a1.y, a1.z, a1.w};
  float s = 0.f;
#pragma unroll
  for (int j = 0; j < 8; ++j) s += v[j] * v[j];
#pragma unroll
  for (int o = 32; o; o >>= 1) s += __shfl_xor(s, o);
  __shared__ float red[4];
  if ((tid & 63) == 0) red[tid >> 6] = s;
  __syncthreads();
  const float tot = red[0] + red[1] + red[2] + red[3];
  const float inv = 1.f / (sqrtf(tot * (1.f / 2048.f)) + 1e-8f);
  bf16x8 g8 = *(const bf16x8*)(g + tid * 8);
  bf16x8 o8;
#pragma unroll
  for (int j = 0; j < 8; ++j) o8[j] = (bf16)((float)g8[j] * v[j] * inv);
  *(bf16x8*)(Hout + off) = o8;
}

// ---------------------------------------------------------------------------
// RoPE in-place on Q and K.
// ---------------------------------------------------------------------------
__global__ __launch_bounds__(256) void rope_k(bf16* __restrict__ Q, bf16* __restrict__ Kg,
                                              const bf16* __restrict__ cosb,
                                              const bf16* __restrict__ sinb) {
  const int tid = threadIdx.x;
  const int rr = tid >> 7;
  const int c = tid & 127;
  const int bt = blockIdx.x * 2 + rr;
  const int t = bt & 2047;
  const int h = c >> 3;
  const int d0 = (c & 7) * 8;
  const size_t row = (size_t)bt * 2048;
  const int i0 = h * 128 + d0;
  bf16x8 c0 = *(const bf16x8*)(cosb + t * 128 + d0);
  bf16x8 c1 = *(const bf16x8*)(cosb + t * 128 + d0 + 64);
  bf16x8 s0 = *(const bf16x8*)(sinb + t * 128 + d0);
  bf16x8 s1 = *(const bf16x8*)(sinb + t * 128 + d0 + 64);
  bf16x8 qa = *(const bf16x8*)(Q + row + i0);
  bf16x8 qb = *(const bf16x8*)(Q + row + i0 + 64);
  bf16x8 ka = *(const bf16x8*)(Kg + row + i0);
  bf16x8 kb = *(const bf16x8*)(Kg + row + i0 + 64);
  bf16x8 qo0, qo1, ko0, ko1;
#pragma unroll
  for (int j = 0; j < 8; ++j) {
    float cj0 = (float)c0[j], cj1 = (float)c1[j];
    float sj0 = (float)s0[j], sj1 = (float)s1[j];
    float qaj = (float)qa[j], qbj = (float)qb[j];
    float kaj = (float)ka[j], kbj = (float)kb[j];
    qo0[j] = (bf16)(qaj * cj0 - qbj * sj0);
    qo1[j] = (bf16)(qbj * cj1 + qaj * sj1);
    ko0[j] = (bf16)(kaj * cj0 - kbj * sj0);
    ko1[j] = (bf16)(kbj * cj1 + kaj * sj1);
  }
  *(bf16x8*)(Q + row + i0) = qo0;
  *(bf16x8*)(Q + row + i0 + 64) = qo1;
  *(bf16x8*)(Kg + row + i0) = ko0;
  *(bf16x8*)(Kg + row + i0 + 64) = ko1;
}

// ---------------------------------------------------------------------------
// GEMM C = A(MxK) * W(NxK)^T, bf16 MFMA 16x16x32, 128x128 tile, 4 waves 2x2.
// Double-buffered LDS: stage(k+1) issued after the barrier, overlapping MFMA(k).
// EPI: 0 bf16; 1 fp32 = v + bf16 res; 2 silu->bf16; 3 v*mulb->bf16;
//      4 fp32 res + v -> d_out (dtype per oflag).
// ---------------------------------------------------------------------------
template <int EPI>
__global__ __launch_bounds__(256) void gemm_bt(const bf16* __restrict__ A,
                                               const bf16* __restrict__ W,
                                               bf16* __restrict__ Cb, float* __restrict__ Cf,
                                               const bf16* __restrict__ resb,
                                               const float* __restrict__ resf,
                                               const bf16* __restrict__ mulb,
                                               const int* __restrict__ oflag,
                                               int M, int N, int K) {
  __shared__ bf16 As[2][128 * 32];
  __shared__ bf16 Ws[2][128 * 32];
  const int tid = threadIdx.x;
  const int wave = tid >> 6, lane = tid & 63;
  const int quad = lane >> 4, l15 = lane & 15;
  const int wm = wave >> 1, wn = wave & 1;
  const int m0 = blockIdx.y * 128, n0 = blockIdx.x * 128;

  f32x4 acc[4][4];
#pragma unroll
  for (int i = 0; i < 4; ++i)
#pragma unroll
    for (int j = 0; j < 4; ++j) acc[i][j] = {0.f, 0.f, 0.f, 0.f};

  const int srow = lane >> 2;       // 0..15
  const int skk = (lane & 3) * 8;   // 0,8,16,24
  const bf16* Ab = A + (size_t)m0 * K;
  const bf16* Wb = W + (size_t)n0 * K;

  // stage one 128x32 K-slice of A and W into buffer `buf` (async, 16B/lane)
  auto stage = [&](int buf, int kb) {
    const int k0 = kb << 5;
#pragma unroll
    for (int c = 0; c < 2; ++c) {
      const int r = (wave * 2 + c) * 16 + srow;
      gld_lds16(Ab + (size_t)r * K + k0 + skk, (char*)As[buf] + (wave * 2 + c) * 1024);
      gld_lds16(Wb + (size_t)r * K + k0 + skk, (char*)Ws[buf] + (wave * 2 + c) * 1024);
    }
  };
  // ds_read frags from buffer `buf` and run 16 MFMAs
  auto compute = [&](int buf) {
    bf16x8 af[4], wf[4];
#pragma unroll
    for (int mt = 0; mt < 4; ++mt)
      af[mt] = *(const bf16x8*)&As[buf][(wm * 64 + mt * 16 + l15) * 32 + quad * 8];
#pragma unroll
    for (int nt = 0; nt < 4; ++nt)
      wf[nt] = *(const bf16x8*)&Ws[buf][(wn * 64 + nt * 16 + l15) * 32 + quad * 8];
#pragma unroll
    for (int mt = 0; mt < 4; ++mt)
#pragma unroll
      for (int nt = 0; nt < 4; ++nt)
        acc[mt][nt] = MFMA_BF16(af[mt], wf[nt], acc[mt][nt]);
  };

  const int nk = K >> 5;  // always even here (64 or 172)
  stage(0, 0);
  for (int kb = 0; kb < nk; kb += 2) {
    __syncthreads();                     // buf0 loads drained (vmcnt0) + reads of buf0 done
    if (kb + 1 < nk) stage(1, kb + 1);   // overlaps compute(buf0)
    compute(0);
    __syncthreads();                     // buf1 loads drained + reads of buf1 done
    if (kb + 2 < nk) stage(0, kb + 2);   // overlaps compute(buf1)
    compute(1);
  }

  const int obf = (EPI == 4 && oflag) ? *oflag : 0;
#pragma unroll
  for (int mt = 0; mt < 4; ++mt) {
#pragma unroll
    for (int nt = 0; nt < 4; ++nt) {
#pragma unroll
      for (int r = 0; r < 4; ++r) {
        const int row = m0 + wm * 64 + mt * 16 + quad * 4 + r;
        const int col = n0 + wn * 64 + nt * 16 + l15;
        const size_t idx = (size_t)row * N + col;
        const float v = acc[mt][nt][r];
        if constexpr (EPI == 0) {
          Cb[idx] = (bf16)v;
        } else if constexpr (EPI == 1) {
          Cf[idx] = v + (float)resb[idx];
        } else if constexpr (EPI == 2) {
          Cb[idx] = (bf16)(v / (1.f + __expf(-v)));   // silu
        } else if constexpr (EPI == 3) {
          Cb[idx] = (bf16)((float)mulb[idx] * v);
        } else {  // EPI == 4: final output, dtype per flag
          const float rres = resf[idx] + v;
          if (obf) Cb[idx] = (bf16)rres;
          else     Cf[idx] = rres;
        }
      }
    }
  }
}

// ---------------------------------------------------------------------------
// Flash attention (causal). Grid (16, B*H); block x handles q-tiles x and 31-x
// (33 k-iterations per block — balanced). K/V double-buffered in LDS (72KB,
// 2 blocks/CU); ONE barrier per iteration; next-tile K DMA + V reg-loads issued
// right after the barrier so latency hides under QK+softmax+PV of current tile.
// All LDS XOR-swizzled (byte ^= ((row&7)<<4)); K staged by global_load_lds with
// pre-swizzled SOURCE (linear LDS dest).
// ---------------------------------------------------------------------------
__global__ __launch_bounds__(256) void flash_attn(const bf16* __restrict__ Q,
                                                  const bf16* __restrict__ Kg,
                                                  const bf16* __restrict__ Vg,
                                                  bf16* __restrict__ O) {
  __shared__ bf16 Ks[2][64 * 128];    // 2 x 16KB, 256B/row, swizzled
  __shared__ bf16 Vt[2][128 * 64];    // 2 x 16KB, V^T d-major, 128B/row, swizzled
  __shared__ bf16 Ps[4 * 16 * 64];    // 8KB per-wave P tile, swizzled
  const int tid = threadIdx.x;
  const int wave = tid >> 6, lane = tid & 63;
  const int quad = lane >> 4, l15 = lane & 15;
  const int bh = blockIdx.y;
  const int b = bh >> 4, h = bh & 15;
  const size_t base = (size_t)b * 2048 * 2048 + h * 128;
  const float scale = 0.08838834764831845f;  // 1/sqrt(128)

  bf16x8 vva[2], vvb[2];  // V tile in-flight registers (tile kb+1 during iter kb)

  auto stageK = [&](int buf, int kb) {
    const int k0 = kb * 64;
#pragma unroll
    for (int c = 0; c < 4; ++c) {
      const int ch = tid + 256 * c;
      const int row = ch >> 4;
      const int scb = ((ch & 15) * 16) ^ ((row & 7) << 4);  // pre-swizzled src col
      gld_lds16((const char*)(Kg + base + (size_t)(k0 + row) * 2048) + scb,
                (char*)Ks[buf] + wave * 1024 + c * 4096);   // wave-uniform + lane*16
    }
  };
  auto loadV = [&](int kb) {
    const int k0 = kb * 64;
#pragma unroll
    for (int c = 0; c < 2; ++c) {
      const int tau = tid + 256 * c;
      const int kp = tau & 31;
      const int d0 = (tau >> 5) * 8;
      vva[c] = *(const bf16x8*)(Vg + base + (size_t)(k0 + 2 * kp) * 2048 + d0);
      vvb[c] = *(const bf16x8*)(Vg + base + (size_t)(k0 + 2 * kp + 1) * 2048 + d0);
    }
  };
  auto writeV = [&](int buf) {
#pragma unroll
    for (int c = 0; c < 2; ++c) {
      const int tau = tid + 256 * c;
      const int kp = tau & 31;
      const int d0 = (tau >> 5) * 8;
#pragma unroll
      for (int j = 0; j < 8; ++j) {
        bf16x2 pr = {vva[c][j], vvb[c][j]};
        const int d = d0 + j;
        *(bf16x2*)((char*)Vt[buf] + d * 128 + ((4 * kp) ^ ((d & 7) << 4))) = pr;
      }
    }
  };

#pragma unroll 1
  for (int half = 0; half < 2; ++half) {
    const int qt = half ? (31 - (int)blockIdx.x) : (int)blockIdx.x;
    const int q0 = qt * 64;

    bf16x8 qf[4];
    {
      const bf16* qrow = Q + base + (size_t)(q0 + wave * 16 + l15) * 2048;
#pragma unroll
      for (int ks = 0; ks < 4; ++ks) qf[ks] = *(const bf16x8*)(qrow + ks * 32 + quad * 8);
    }

    f32x4 o[8];
#pragma unroll
    for (int i = 0; i < 8; ++i) o[i] = {0.f, 0.f, 0.f, 0.f};
    float m_r[4] = {-1e30f, -1e30f, -1e30f, -1e30f};
    float l_r[4] = {0.f, 0.f, 0.f, 0.f};

    // ---- prologue: stage tile 0; prefetch tile 1
    __syncthreads();            // previous half's LDS reads retired
    loadV(0);
    stageK(0, 0);
    writeV(0);                  // waits vmcnt for V regs (older), K DMA may fly on
    __syncthreads();            // K(0) DMA drained + Vt(0) visible
    if (qt >= 1) { loadV(1); stageK(1, 1); }

#pragma unroll 1
    for (int kb = 0; kb <= qt; ++kb) {
      const int cur = kb & 1;
      const int k0 = kb * 64;

      // ---- QK^T from Ks[cur]
      f32x4 s[4];
#pragma unroll
      for (int nt = 0; nt < 4; ++nt) {
        s[nt] = {0.f, 0.f, 0.f, 0.f};
        const int krow = nt * 16 + l15;
#pragma unroll
        for (int ks = 0; ks < 4; ++ks) {
          bf16x8 kf = *(const bf16x8*)((char*)Ks[cur] + krow * 256 +
                                       ((ks * 64 + quad * 16) ^ ((krow & 7) << 4)));
          s[nt] = MFMA_BF16(qf[ks], kf, s[nt]);
        }
      }

      // ---- mask + scale
      float sv[4][4];
#pragma unroll
      for (int nt = 0; nt < 4; ++nt) {
#pragma unroll
        for (int r = 0; r < 4; ++r) {
          float v = s[nt][r] * scale;
          const int key = k0 + nt * 16 + l15;
          const int qq = q0 + wave * 16 + quad * 4 + r;
          if (key > qq) v = -1e9f;
          sv[nt][r] = v;
        }
      }

      // ---- online softmax (wave-parallel), P -> Ps (swizzled)
#pragma unroll
      for (int r = 0; r < 4; ++r) {
        float rmax = fmaxf(fmaxf(sv[0][r], sv[1][r]), fmaxf(sv[2][r], sv[3][r]));
#pragma unroll
        for (int off = 1; off < 16; off <<= 1) rmax = fmaxf(rmax, __shfl_xor(rmax, off));
        const float mnew = fmaxf(m_r[r], rmax);
        const float alpha = __expf(m_r[r] - mnew);
        float psum = 0.f;
        const int qrow = quad * 4 + r;
#pragma unroll
        for (int nt = 0; nt < 4; ++nt) {
          const float p = __expf(sv[nt][r] - mnew);
          psum += p;
          *(bf16*)((char*)Ps + wave * 2048 + qrow * 128 +
                   ((2 * (nt * 16 + l15)) ^ ((qrow & 7) << 4))) = (bf16)p;
        }
#pragma unroll
        for (int off = 1; off < 16; off <<= 1) psum += __shfl_xor(psum, off);
        l_r[r] = l_r[r] * alpha + psum;
        m_r[r] = mnew;
#pragma unroll
        for (int nt2 = 0; nt2 < 8; ++nt2) o[nt2][r] *= alpha;
      }

      asm volatile("s_waitcnt lgkmcnt(0)" ::: "memory");

      // ---- PV from Ps & Vt[cur]
#pragma unroll
      for (int ks2 = 0; ks2 < 2; ++ks2) {
        bf16x8 pf = *(const bf16x8*)((char*)Ps + wave * 2048 + l15 * 128 +
                                     ((ks2 * 64 + quad * 16) ^ ((l15 & 7) << 4)));
#pragma unroll
        for (int nt2 = 0; nt2 < 8; ++nt2) {
          const int drow = nt2 * 16 + l15;
          bf16x8 vf = *(const bf16x8*)((char*)Vt[cur] + drow * 128 +
                                       ((ks2 * 64 + quad * 16) ^ ((drow & 7) << 4)));
          o[nt2] = MFMA_BF16(pf, vf, o[nt2]);
        }
      }

      // ---- stage V(kb+1) regs -> Vt[cur^1] (loads issued last iteration)
      if (kb + 1 <= qt) writeV(cur ^ 1);

      __syncthreads();   // K(kb+1) DMA drained; Vt(kb+1) visible; both bufs' readers retired
      if (kb + 2 <= qt) { loadV(kb + 2); stageK(cur, kb + 2); }  // a full iter ahead
    }

    // ---- epilogue: O = o / l
#pragma unroll
    for (int nt2 = 0; nt2 < 8; ++nt2) {
#pragma unroll
      for (int r = 0; r < 4; ++r) {
        const int qq = q0 + wave * 16 + quad * 4 + r;
        const int dd = nt2 * 16 + l15;
        O[base + (size_t)qq * 2048 + dd] = (bf16)(o[nt2][r] / l_r[r]);
      }
    }
  }
}

// ---------------------------------------------------------------------------
extern "C" void kernel_launch(void* const* d_in, const int* in_sizes, int n_in,
                              void* d_out, int out_size, void* d_ws, size_t ws_size,
                              hipStream_t stream) {
  const void* x_raw = d_in[0];
  const void* cos_raw = d_in[1];
  const void* sin_raw = d_in[2];
  // d_in[3] = mask — causal, applied analytically in flash_attn
  const void* g1_raw = d_in[4];
  const void* g2_raw = d_in[5];
  const void* W_raw[7] = {d_in[6], d_in[7], d_in[8], d_in[9], d_in[10], d_in[11], d_in[12]};

  char* ws = (char*)d_ws;
  const size_t MB = 1048576ull;
  int* flag = (int*)ws;
  bf16* g1c = (bf16*)(ws + 4096);
  bf16* g2c = (bf16*)(ws + 12288);
  bf16* cosc = (bf16*)(ws + 65536);          // 512KB
  bf16* sinc = (bf16*)(ws + 655360);         // 512KB
  bf16* xc   = (bf16*)(ws + 2 * MB);         // 16MB  [2,18)
  bf16* wslot= (bf16*)(ws + 18 * MB);        // 23MB  [18,41)
  bf16* hbuf = (bf16*)(ws + 41 * MB);        // 16MB  [41,57)
  bf16* qbuf = (bf16*)(ws + 57 * MB);        // 16MB  [57,73)
  bf16* kbuf = (bf16*)(ws + 73 * MB);        // 16MB  [73,89)
  bf16* vbuf = (bf16*)(ws + 89 * MB);        // 16MB  [89,105)
  bf16* abuf = (bf16*)(ws + 105 * MB);       // 16MB  [105,121)
  float* x1  = (float*)(ws + 57 * MB);       // 32MB over q,k (dead after flash)
  bf16* h2   = (bf16*)(ws + 41 * MB);        // over h (dead after V gemm)
  bf16* ubuf = (bf16*)(ws + 89 * MB);        // 43MB over v,attn [89,132)

  const int M = 4096;  // B*T
  dim3 blk(256);

  detect_dtype<<<1, 64, 0, stream>>>((const unsigned int*)x_raw, flag);

  convert_in<<<4096, blk, 0, stream>>>(x_raw, xc, flag);
  convert_in<<<128, blk, 0, stream>>>(cos_raw, cosc, flag);
  convert_in<<<128, blk, 0, stream>>>(sin_raw, sinc, flag);
  convert_in<<<1, blk, 0, stream>>>(g1_raw, g1c, flag);
  convert_in<<<1, blk, 0, stream>>>(g2_raw, g2c, flag);

  rmsnorm_bf16<<<M, blk, 0, stream>>>(xc, g1c, hbuf);

  convert_in<<<2048, blk, 0, stream>>>(W_raw[0], wslot, flag);
  gemm_bt<0><<<dim3(16, 32), blk, 0, stream>>>(hbuf, wslot, qbuf, nullptr, nullptr, nullptr, nullptr, nullptr, M, 2048, 2048);
  convert_in<<<2048, blk, 0, stream>>>(W_raw[1], wslot, flag);
  gemm_bt<0><<<dim3(16, 32), blk, 0, stream>>>(hbuf, wslot, kbuf, nullptr, nullptr, nullptr, nullptr, nullptr, M, 2048, 2048);
  convert_in<<<2048, blk, 0, stream>>>(W_raw[2], wslot, flag);
  gemm_bt<0><<<dim3(16, 32), blk, 0, stream>>>(hbuf, wslot, vbuf, nullptr, nullptr, nullptr, nullptr, nullptr, M, 2048, 2048);

  rope_k<<<M / 2, blk, 0, stream>>>(qbuf, kbuf, cosc, sinc);
  flash_attn<<<dim3(16, 32), blk, 0, stream>>>(qbuf, kbuf, vbuf, abuf);

  convert_in<<<2048, blk, 0, stream>>>(W_raw[3], wslot, flag);
  gemm_bt<1><<<dim3(16, 32), blk, 0, stream>>>(abuf, wslot, nullptr, x1, xc, nullptr, nullptr, nullptr, M, 2048, 2048);

  rmsnorm_f32<<<M, blk, 0, stream>>>(x1, g2c, h2);

  convert_in<<<5504, blk, 0, stream>>>(W_raw[4], wslot, flag);
  gemm_bt<2><<<dim3(43, 32), blk, 0, stream>>>(h2, wslot, ubuf, nullptr, nullptr, nullptr, nullptr, nullptr, M, 5504, 2048);
  convert_in<<<5504, blk, 0, stream>>>(W_raw[5], wslot, flag);
  gemm_bt<3><<<dim3(43, 32), blk, 0, stream>>>(h2, wslot, ubuf, nullptr, nullptr, nullptr, ubuf, nullptr, M, 5504, 2048);
  convert_in<<<5504, blk, 0, stream>>>(W_raw[6], wslot, flag);
  gemm_bt<4><<<dim3(16, 32), blk, 0, stream>>>(ubuf, wslot, (bf16*)d_out, (float*)d_out, nullptr, x1, nullptr, flag, M, 2048, 5504);
}

// Round 3
// 991.403 us; speedup vs baseline: 1.0974x; 1.0810x over previous
//
#include <hip/hip_runtime.h>

// TransformerBlock on MI355X (gfx950). B=2 T=2048 D_MODEL=2048 H=16 HD=128 D_FF=5504.
// Round 8: flash_attn —
//   * LDS 56KB (Ks dbuf 32K + Vt single 16K + Ps 8K) -> 2 blocks/CU restored
//   * raw s_barrier + counted s_waitcnt vmcnt(8) (T3/T4): prefetches (K DMA 2 iters
//     ahead, V regs 1 iter ahead) survive barriers; never vmcnt(0) in the loop
//   * grid (bh=32, pair=16): id%8 = bh%8 -> all blocks of a head on one XCD,
//     K/V (1MB/head, 4 heads/XCD) become L2-resident
//   * s_setprio(1) around MFMA clusters

using bf16 = __bf16;
typedef __bf16 bf16x2 __attribute__((ext_vector_type(2)));
typedef __bf16 bf16x8 __attribute__((ext_vector_type(8)));
typedef float f32x4 __attribute__((ext_vector_type(4)));

#define MFMA_BF16(a, b, c) __builtin_amdgcn_mfma_f32_16x16x32_bf16((a), (b), (c), 0, 0, 0)

__device__ __forceinline__ void gld_lds16(const void* g, void* l) {
  // async global->LDS; LDS dst = wave-uniform base + lane*16 (HW rule).
  __builtin_amdgcn_global_load_lds((const __attribute__((address_space(1))) void*)g,
                                   (__attribute__((address_space(3))) void*)l,
                                   16, 0, 0);
}

// ---------------------------------------------------------------------------
// Detect input dtype (fp32 vs bf16) from x's first 64 words. flag=1 -> bf16.
// ---------------------------------------------------------------------------
__global__ void detect_dtype(const unsigned int* __restrict__ X, int* __restrict__ flag) {
  const int tid = threadIdx.x;  // 64 threads = 1 wave
  const unsigned int w = X[tid];
  const unsigned int e_lo = (w >> 7) & 0xFF;
  const unsigned int e_hi = (w >> 23) & 0xFF;
  const bool sane = (e_lo >= 97u && e_lo <= 157u) && (e_hi >= 97u && e_hi <= 157u);
  const unsigned long long m = __ballot(sane);
  if (tid == 0) *flag = (__popcll(m) > 48) ? 1 : 0;
}

__global__ __launch_bounds__(256) void convert_in(const void* __restrict__ src,
                                                  bf16* __restrict__ dst,
                                                  const int* __restrict__ flag) {
  const size_t i = ((size_t)blockIdx.x * 256 + threadIdx.x) * 8;
  if (*flag) {
    *(bf16x8*)(dst + i) = *(const bf16x8*)((const bf16*)src + i);
  } else {
    const float* s = (const float*)src;
    float4 a = *(const float4*)(s + i);
    float4 b = *(const float4*)(s + i + 4);
    bf16x8 o;
    o[0] = (bf16)a.x; o[1] = (bf16)a.y; o[2] = (bf16)a.z; o[3] = (bf16)a.w;
    o[4] = (bf16)b.x; o[5] = (bf16)b.y; o[6] = (bf16)b.z; o[7] = (bf16)b.w;
    *(bf16x8*)(dst + i) = o;
  }
}

// ---------------------------------------------------------------------------
// RMSNorm kernels (fp32 math).
// ---------------------------------------------------------------------------
__global__ __launch_bounds__(256) void rmsnorm_bf16(const bf16* __restrict__ X,
                                                    const bf16* __restrict__ g,
                                                    bf16* __restrict__ Hout) {
  const int row = blockIdx.x, tid = threadIdx.x;
  const size_t off = (size_t)row * 2048 + tid * 8;
  bf16x8 x8 = *(const bf16x8*)(X + off);
  float v[8];
  float s = 0.f;
#pragma unroll
  for (int j = 0; j < 8; ++j) { v[j] = (float)x8[j]; s += v[j] * v[j]; }
#pragma unroll
  for (int o = 32; o; o >>= 1) s += __shfl_xor(s, o);
  __shared__ float red[4];
  if ((tid & 63) == 0) red[tid >> 6] = s;
  __syncthreads();
  const float tot = red[0] + red[1] + red[2] + red[3];
  const float inv = 1.f / (sqrtf(tot * (1.f / 2048.f)) + 1e-8f);
  bf16x8 g8 = *(const bf16x8*)(g + tid * 8);
  bf16x8 o8;
#pragma unroll
  for (int j = 0; j < 8; ++j) o8[j] = (bf16)((float)g8[j] * v[j] * inv);
  *(bf16x8*)(Hout + off) = o8;
}

__global__ __launch_bounds__(256) void rmsnorm_f32(const float* __restrict__ X,
                                                   const bf16* __restrict__ g,
                                                   bf16* __restrict__ Hout) {
  const int row = blockIdx.x, tid = threadIdx.x;
  const size_t off = (size_t)row * 2048 + tid * 8;
  float4 a0 = *(const float4*)(X + off);
  float4 a1 = *(const float4*)(X + off + 4);
  float v[8] = {a0.x, a0.y, a0.z, a0.w, a1.x, a1.y, a1.z, a1.w};
  float s = 0.f;
#pragma unroll
  for (int j = 0; j < 8; ++j) s += v[j] * v[j];
#pragma unroll
  for (int o = 32; o; o >>= 1) s += __shfl_xor(s, o);
  __shared__ float red[4];
  if ((tid & 63) == 0) red[tid >> 6] = s;
  __syncthreads();
  const float tot = red[0] + red[1] + red[2] + red[3];
  const float inv = 1.f / (sqrtf(tot * (1.f / 2048.f)) + 1e-8f);
  bf16x8 g8 = *(const bf16x8*)(g + tid * 8);
  bf16x8 o8;
#pragma unroll
  for (int j = 0; j < 8; ++j) o8[j] = (bf16)((float)g8[j] * v[j] * inv);
  *(bf16x8*)(Hout + off) = o8;
}

// ---------------------------------------------------------------------------
// RoPE in-place on Q and K.
// ---------------------------------------------------------------------------
__global__ __launch_bounds__(256) void rope_k(bf16* __restrict__ Q, bf16* __restrict__ Kg,
                                              const bf16* __restrict__ cosb,
                                              const bf16* __restrict__ sinb) {
  const int tid = threadIdx.x;
  const int rr = tid >> 7;
  const int c = tid & 127;
  const int bt = blockIdx.x * 2 + rr;
  const int t = bt & 2047;
  const int h = c >> 3;
  const int d0 = (c & 7) * 8;
  const size_t row = (size_t)bt * 2048;
  const int i0 = h * 128 + d0;
  bf16x8 c0 = *(const bf16x8*)(cosb + t * 128 + d0);
  bf16x8 c1 = *(const bf16x8*)(cosb + t * 128 + d0 + 64);
  bf16x8 s0 = *(const bf16x8*)(sinb + t * 128 + d0);
  bf16x8 s1 = *(const bf16x8*)(sinb + t * 128 + d0 + 64);
  bf16x8 qa = *(const bf16x8*)(Q + row + i0);
  bf16x8 qb = *(const bf16x8*)(Q + row + i0 + 64);
  bf16x8 ka = *(const bf16x8*)(Kg + row + i0);
  bf16x8 kb = *(const bf16x8*)(Kg + row + i0 + 64);
  bf16x8 qo0, qo1, ko0, ko1;
#pragma unroll
  for (int j = 0; j < 8; ++j) {
    float cj0 = (float)c0[j], cj1 = (float)c1[j];
    float sj0 = (float)s0[j], sj1 = (float)s1[j];
    float qaj = (float)qa[j], qbj = (float)qb[j];
    float kaj = (float)ka[j], kbj = (float)kb[j];
    qo0[j] = (bf16)(qaj * cj0 - qbj * sj0);
    qo1[j] = (bf16)(qbj * cj1 + qaj * sj1);
    ko0[j] = (bf16)(kaj * cj0 - kbj * sj0);
    ko1[j] = (bf16)(kbj * cj1 + kaj * sj1);
  }
  *(bf16x8*)(Q + row + i0) = qo0;
  *(bf16x8*)(Q + row + i0 + 64) = qo1;
  *(bf16x8*)(Kg + row + i0) = ko0;
  *(bf16x8*)(Kg + row + i0 + 64) = ko1;
}

// ---------------------------------------------------------------------------
// GEMM C = A(MxK) * W(NxK)^T, bf16 MFMA 16x16x32, 128x128 tile, 4 waves 2x2.
// Double-buffered LDS: stage(k+1) issued after the barrier, overlapping MFMA(k).
// EPI: 0 bf16; 1 fp32 = v + bf16 res; 2 silu->bf16; 3 v*mulb->bf16;
//      4 fp32 res + v -> d_out (dtype per oflag).
// ---------------------------------------------------------------------------
template <int EPI>
__global__ __launch_bounds__(256) void gemm_bt(const bf16* __restrict__ A,
                                               const bf16* __restrict__ W,
                                               bf16* __restrict__ Cb, float* __restrict__ Cf,
                                               const bf16* __restrict__ resb,
                                               const float* __restrict__ resf,
                                               const bf16* __restrict__ mulb,
                                               const int* __restrict__ oflag,
                                               int M, int N, int K) {
  __shared__ bf16 As[2][128 * 32];
  __shared__ bf16 Ws[2][128 * 32];
  const int tid = threadIdx.x;
  const int wave = tid >> 6, lane = tid & 63;
  const int quad = lane >> 4, l15 = lane & 15;
  const int wm = wave >> 1, wn = wave & 1;
  const int m0 = blockIdx.y * 128, n0 = blockIdx.x * 128;

  f32x4 acc[4][4];
#pragma unroll
  for (int i = 0; i < 4; ++i)
#pragma unroll
    for (int j = 0; j < 4; ++j) acc[i][j] = {0.f, 0.f, 0.f, 0.f};

  const int srow = lane >> 2;       // 0..15
  const int skk = (lane & 3) * 8;   // 0,8,16,24
  const bf16* Ab = A + (size_t)m0 * K;
  const bf16* Wb = W + (size_t)n0 * K;

  // stage one 128x32 K-slice of A and W into buffer `buf` (async, 16B/lane)
  auto stage = [&](int buf, int kb) {
    const int k0 = kb << 5;
#pragma unroll
    for (int c = 0; c < 2; ++c) {
      const int r = (wave * 2 + c) * 16 + srow;
      gld_lds16(Ab + (size_t)r * K + k0 + skk, (char*)As[buf] + (wave * 2 + c) * 1024);
      gld_lds16(Wb + (size_t)r * K + k0 + skk, (char*)Ws[buf] + (wave * 2 + c) * 1024);
    }
  };
  // ds_read frags from buffer `buf` and run 16 MFMAs
  auto compute = [&](int buf) {
    bf16x8 af[4], wf[4];
#pragma unroll
    for (int mt = 0; mt < 4; ++mt)
      af[mt] = *(const bf16x8*)&As[buf][(wm * 64 + mt * 16 + l15) * 32 + quad * 8];
#pragma unroll
    for (int nt = 0; nt < 4; ++nt)
      wf[nt] = *(const bf16x8*)&Ws[buf][(wn * 64 + nt * 16 + l15) * 32 + quad * 8];
#pragma unroll
    for (int mt = 0; mt < 4; ++mt)
#pragma unroll
      for (int nt = 0; nt < 4; ++nt)
        acc[mt][nt] = MFMA_BF16(af[mt], wf[nt], acc[mt][nt]);
  };

  const int nk = K >> 5;  // always even here (64 or 172)
  stage(0, 0);
  for (int kb = 0; kb < nk; kb += 2) {
    __syncthreads();                     // buf0 loads drained (vmcnt0) + reads of buf0 done
    if (kb + 1 < nk) stage(1, kb + 1);   // overlaps compute(buf0)
    compute(0);
    __syncthreads();                     // buf1 loads drained + reads of buf1 done
    if (kb + 2 < nk) stage(0, kb + 2);   // overlaps compute(buf1)
    compute(1);
  }

  const int obf = (EPI == 4 && oflag) ? *oflag : 0;
#pragma unroll
  for (int mt = 0; mt < 4; ++mt) {
#pragma unroll
    for (int nt = 0; nt < 4; ++nt) {
#pragma unroll
      for (int r = 0; r < 4; ++r) {
        const int row = m0 + wm * 64 + mt * 16 + quad * 4 + r;
        const int col = n0 + wn * 64 + nt * 16 + l15;
        const size_t idx = (size_t)row * N + col;
        const float v = acc[mt][nt][r];
        if constexpr (EPI == 0) {
          Cb[idx] = (bf16)v;
        } else if constexpr (EPI == 1) {
          Cf[idx] = v + (float)resb[idx];
        } else if constexpr (EPI == 2) {
          Cb[idx] = (bf16)(v / (1.f + __expf(-v)));   // silu
        } else if constexpr (EPI == 3) {
          Cb[idx] = (bf16)((float)mulb[idx] * v);
        } else {  // EPI == 4: final output, dtype per flag
          const float rres = resf[idx] + v;
          if (obf) Cb[idx] = (bf16)rres;
          else     Cf[idx] = rres;
        }
      }
    }
  }
}

// ---------------------------------------------------------------------------
// Flash attention (causal). Grid (32 bh, 16 pair); block handles q-tiles pr and
// 31-pr (33 iters, balanced). LDS 56KB -> 2 blocks/CU. Raw s_barrier + counted
// vmcnt: K DMA'd 2 iters ahead (double-buffered, pre-swizzled source), V regs
// loaded 1 iter ahead and ds_written at top of iter (single Vt buffer).
// All LDS XOR-swizzled (byte ^= ((row&7)<<4)).
// ---------------------------------------------------------------------------
__global__ __launch_bounds__(256) void flash_attn(const bf16* __restrict__ Q,
                                                  const bf16* __restrict__ Kg,
                                                  const bf16* __restrict__ Vg,
                                                  bf16* __restrict__ O) {
  __shared__ bf16 Ks[2][64 * 128];    // 2 x 16KB, 256B/row, swizzled
  __shared__ bf16 Vt[128 * 64];       // 16KB, V^T d-major, 128B/row, swizzled
  __shared__ bf16 Ps[4 * 16 * 64];    // 8KB per-wave P tile, swizzled
  const int tid = threadIdx.x;
  const int wave = tid >> 6, lane = tid & 63;
  const int quad = lane >> 4, l15 = lane & 15;
  const int bh = blockIdx.x;          // head-major: id%8 = bh%8 -> XCD locality
  const int b = bh >> 4, h = bh & 15;
  const size_t base = (size_t)b * 2048 * 2048 + h * 128;
  const float scale = 0.08838834764831845f;  // 1/sqrt(128)

  bf16x8 vva[2], vvb[2];  // V tile in-flight regs (tile kb+1 during iter kb)

  auto stageK = [&](int buf, int kb) {
    const int k0 = kb * 64;
#pragma unroll
    for (int c = 0; c < 4; ++c) {
      const int ch = tid + 256 * c;
      const int row = ch >> 4;
      const int scb = ((ch & 15) * 16) ^ ((row & 7) << 4);  // pre-swizzled src col
      gld_lds16((const char*)(Kg + base + (size_t)(k0 + row) * 2048) + scb,
                (char*)Ks[buf] + wave * 1024 + c * 4096);   // wave-uniform + lane*16
    }
  };
  auto loadV = [&](int kb) {
    const int k0 = kb * 64;
#pragma unroll
    for (int c = 0; c < 2; ++c) {
      const int tau = tid + 256 * c;
      const int kp = tau & 31;
      const int d0 = (tau >> 5) * 8;
      vva[c] = *(const bf16x8*)(Vg + base + (size_t)(k0 + 2 * kp) * 2048 + d0);
      vvb[c] = *(const bf16x8*)(Vg + base + (size_t)(k0 + 2 * kp + 1) * 2048 + d0);
    }
  };
  auto writeV = [&]() {
#pragma unroll
    for (int c = 0; c < 2; ++c) {
      const int tau = tid + 256 * c;
      const int kp = tau & 31;
      const int d0 = (tau >> 5) * 8;
#pragma unroll
      for (int j = 0; j < 8; ++j) {
        bf16x2 pr = {vva[c][j], vvb[c][j]};
        const int d = d0 + j;
        *(bf16x2*)((char*)Vt + d * 128 + ((4 * kp) ^ ((d & 7) << 4))) = pr;
      }
    }
  };

#pragma unroll 1
  for (int half = 0; half < 2; ++half) {
    const int qt = half ? (31 - (int)blockIdx.y) : (int)blockIdx.y;
    const int q0 = qt * 64;

    bf16x8 qf[4];
    {
      const bf16* qrow = Q + base + (size_t)(q0 + wave * 16 + l15) * 2048;
#pragma unroll
      for (int ks = 0; ks < 4; ++ks) qf[ks] = *(const bf16x8*)(qrow + ks * 32 + quad * 8);
    }

    f32x4 o[8];
#pragma unroll
    for (int i = 0; i < 8; ++i) o[i] = {0.f, 0.f, 0.f, 0.f};
    float m_r[4] = {-1e30f, -1e30f, -1e30f, -1e30f};
    float l_r[4] = {0.f, 0.f, 0.f, 0.f};

    // ---- prologue: V(0) regs; K(0), K(1) DMAs
    loadV(0);
    stageK(0, 0);
    if (qt >= 1) stageK(1, 1);
    asm volatile("s_waitcnt vmcnt(4)" ::: "memory");  // V(0)+K(0) done; K(1) may fly
    __builtin_amdgcn_s_barrier();
    __builtin_amdgcn_sched_barrier(0);

#pragma unroll 1
    for (int kb = 0; kb <= qt; ++kb) {
      const int cur = kb & 1;
      const int k0 = kb * 64;

      // 1. V(kb) regs -> Vt (prev-iter barrier retired PV(kb-1) readers)
      writeV();
      // 2. prefetch V(kb+1) regs
      if (kb + 1 <= qt) loadV(kb + 1);

      // 3. QK^T from Ks[cur]
      f32x4 s[4];
      __builtin_amdgcn_s_setprio(1);
#pragma unroll
      for (int nt = 0; nt < 4; ++nt) {
        s[nt] = {0.f, 0.f, 0.f, 0.f};
        const int krow = nt * 16 + l15;
#pragma unroll
        for (int ks = 0; ks < 4; ++ks) {
          bf16x8 kf = *(const bf16x8*)((char*)Ks[cur] + krow * 256 +
                                       ((ks * 64 + quad * 16) ^ ((krow & 7) << 4)));
          s[nt] = MFMA_BF16(qf[ks], kf, s[nt]);
        }
      }
      __builtin_amdgcn_s_setprio(0);

      // mask + scale
      float sv[4][4];
#pragma unroll
      for (int nt = 0; nt < 4; ++nt) {
#pragma unroll
        for (int r = 0; r < 4; ++r) {
          float v = s[nt][r] * scale;
          const int key = k0 + nt * 16 + l15;
          const int qq = q0 + wave * 16 + quad * 4 + r;
          if (key > qq) v = -1e9f;
          sv[nt][r] = v;
        }
      }

      // online softmax (wave-parallel), P -> Ps (swizzled)
#pragma unroll
      for (int r = 0; r < 4; ++r) {
        float rmax = fmaxf(fmaxf(sv[0][r], sv[1][r]), fmaxf(sv[2][r], sv[3][r]));
#pragma unroll
        for (int off = 1; off < 16; off <<= 1) rmax = fmaxf(rmax, __shfl_xor(rmax, off));
        const float mnew = fmaxf(m_r[r], rmax);
        const float alpha = __expf(m_r[r] - mnew);
        float psum = 0.f;
        const int qrow = quad * 4 + r;
#pragma unroll
        for (int nt = 0; nt < 4; ++nt) {
          const float p = __expf(sv[nt][r] - mnew);
          psum += p;
          *(bf16*)((char*)Ps + wave * 2048 + qrow * 128 +
                   ((2 * (nt * 16 + l15)) ^ ((qrow & 7) << 4))) = (bf16)p;
        }
#pragma unroll
        for (int off = 1; off < 16; off <<= 1) psum += __shfl_xor(psum, off);
        l_r[r] = l_r[r] * alpha + psum;
        m_r[r] = mnew;
#pragma unroll
        for (int nt2 = 0; nt2 < 8; ++nt2) o[nt2][r] *= alpha;
      }

      // 4+5. mid barrier: Vt(kb)+Ps visible; Ks[cur] readers retired. NO vmcnt drain.
      asm volatile("s_waitcnt lgkmcnt(0)" ::: "memory");
      __builtin_amdgcn_s_barrier();
      __builtin_amdgcn_sched_barrier(0);

      // 6. K(kb+2) DMA into Ks[cur] (QK(kb) readers retired by barrier above)
      if (kb + 2 <= qt) stageK(cur, kb + 2);

      // 7. PV from Ps & Vt
      __builtin_amdgcn_s_setprio(1);
#pragma unroll
      for (int ks2 = 0; ks2 < 2; ++ks2) {
        bf16x8 pf = *(const bf16x8*)((char*)Ps + wave * 2048 + l15 * 128 +
                                     ((ks2 * 64 + quad * 16) ^ ((l15 & 7) << 4)));
#pragma unroll
        for (int nt2 = 0; nt2 < 8; ++nt2) {
          const int drow = nt2 * 16 + l15;
          bf16x8 vf = *(const bf16x8*)((char*)Vt + drow * 128 +
                                       ((ks2 * 64 + quad * 16) ^ ((drow & 7) << 4)));
          o[nt2] = MFMA_BF16(pf, vf, o[nt2]);
        }
      }
      __builtin_amdgcn_s_setprio(0);

      // 8+9. end barrier: PV readers retired; K(kb+1) DMA (issued last iter) drained
      // via vmcnt(8) — leaves this iter's loadV(kb+1)+stageK(kb+2) (8 ops) in flight.
      asm volatile("s_waitcnt lgkmcnt(0)" ::: "memory");
      asm volatile("s_waitcnt vmcnt(8)" ::: "memory");
      __builtin_amdgcn_s_barrier();
      __builtin_amdgcn_sched_barrier(0);
    }

    // ---- epilogue: O = o / l
#pragma unroll
    for (int nt2 = 0; nt2 < 8; ++nt2) {
#pragma unroll
      for (int r = 0; r < 4; ++r) {
        const int qq = q0 + wave * 16 + quad * 4 + r;
        const int dd = nt2 * 16 + l15;
        O[base + (size_t)qq * 2048 + dd] = (bf16)(o[nt2][r] / l_r[r]);
      }
    }
  }
}

// ---------------------------------------------------------------------------
extern "C" void kernel_launch(void* const* d_in, const int* in_sizes, int n_in,
                              void* d_out, int out_size, void* d_ws, size_t ws_size,
                              hipStream_t stream) {
  const void* x_raw = d_in[0];
  const void* cos_raw = d_in[1];
  const void* sin_raw = d_in[2];
  // d_in[3] = mask — causal, applied analytically in flash_attn
  const void* g1_raw = d_in[4];
  const void* g2_raw = d_in[5];
  const void* W_raw[7] = {d_in[6], d_in[7], d_in[8], d_in[9], d_in[10], d_in[11], d_in[12]};

  char* ws = (char*)d_ws;
  const size_t MB = 1048576ull;
  int* flag = (int*)ws;
  bf16* g1c = (bf16*)(ws + 4096);
  bf16* g2c = (bf16*)(ws + 12288);
  bf16* cosc = (bf16*)(ws + 65536);          // 512KB
  bf16* sinc = (bf16*)(ws + 655360);         // 512KB
  bf16* xc   = (bf16*)(ws + 2 * MB);         // 16MB  [2,18)
  bf16* wslot= (bf16*)(ws + 18 * MB);        // 23MB  [18,41)
  bf16* hbuf = (bf16*)(ws + 41 * MB);        // 16MB  [41,57)
  bf16* qbuf = (bf16*)(ws + 57 * MB);        // 16MB  [57,73)
  bf16* kbuf = (bf16*)(ws + 73 * MB);        // 16MB  [73,89)
  bf16* vbuf = (bf16*)(ws + 89 * MB);        // 16MB  [89,105)
  bf16* abuf = (bf16*)(ws + 105 * MB);       // 16MB  [105,121)
  float* x1  = (float*)(ws + 57 * MB);       // 32MB over q,k (dead after flash)
  bf16* h2   = (bf16*)(ws + 41 * MB);        // over h (dead after V gemm)
  bf16* ubuf = (bf16*)(ws + 89 * MB);        // 43MB over v,attn [89,132)

  const int M = 4096;  // B*T
  dim3 blk(256);

  detect_dtype<<<1, 64, 0, stream>>>((const unsigned int*)x_raw, flag);

  convert_in<<<4096, blk, 0, stream>>>(x_raw, xc, flag);
  convert_in<<<128, blk, 0, stream>>>(cos_raw, cosc, flag);
  convert_in<<<128, blk, 0, stream>>>(sin_raw, sinc, flag);
  convert_in<<<1, blk, 0, stream>>>(g1_raw, g1c, flag);
  convert_in<<<1, blk, 0, stream>>>(g2_raw, g2c, flag);

  rmsnorm_bf16<<<M, blk, 0, stream>>>(xc, g1c, hbuf);

  convert_in<<<2048, blk, 0, stream>>>(W_raw[0], wslot, flag);
  gemm_bt<0><<<dim3(16, 32), blk, 0, stream>>>(hbuf, wslot, qbuf, nullptr, nullptr, nullptr, nullptr, nullptr, M, 2048, 2048);
  convert_in<<<2048, blk, 0, stream>>>(W_raw[1], wslot, flag);
  gemm_bt<0><<<dim3(16, 32), blk, 0, stream>>>(hbuf, wslot, kbuf, nullptr, nullptr, nullptr, nullptr, nullptr, M, 2048, 2048);
  convert_in<<<2048, blk, 0, stream>>>(W_raw[2], wslot, flag);
  gemm_bt<0><<<dim3(16, 32), blk, 0, stream>>>(hbuf, wslot, vbuf, nullptr, nullptr, nullptr, nullptr, nullptr, M, 2048, 2048);

  rope_k<<<M / 2, blk, 0, stream>>>(qbuf, kbuf, cosc, sinc);
  flash_attn<<<dim3(32, 16), blk, 0, stream>>>(qbuf, kbuf, vbuf, abuf);

  convert_in<<<2048, blk, 0, stream>>>(W_raw[3], wslot, flag);
  gemm_bt<1><<<dim3(16, 32), blk, 0, stream>>>(abuf, wslot, nullptr, x1, xc, nullptr, nullptr, nullptr, M, 2048, 2048);

  rmsnorm_f32<<<M, blk, 0, stream>>>(x1, g2c, h2);

  convert_in<<<5504, blk, 0, stream>>>(W_raw[4], wslot, flag);
  gemm_bt<2><<<dim3(43, 32), blk, 0, stream>>>(h2, wslot, ubuf, nullptr, nullptr, nullptr, nullptr, nullptr, M, 5504, 2048);
  convert_in<<<5504, blk, 0, stream>>>(W_raw[5], wslot, flag);
  gemm_bt<3><<<dim3(43, 32), blk, 0, stream>>>(h2, wslot, ubuf, nullptr, nullptr, nullptr, ubuf, nullptr, M, 5504, 2048);
  convert_in<<<5504, blk, 0, stream>>>(W_raw[6], wslot, flag);
  gemm_bt<4><<<dim3(16, 32), blk, 0, stream>>>(ubuf, wslot, (bf16*)d_out, (float*)d_out, nullptr, x1, nullptr, flag, M, 2048, 5504);
}